// Round 6
// baseline (438.139 us; speedup 1.0000x reference)
//
#include <hip/hip_runtime.h>
#include <hip/hip_bf16.h>

#define BR_N     1000000
#define DIM      128
#define TILE_M   64
#define NTILES   (BR_N / TILE_M)   /* 15625, exact */
#define NTHREADS 512
#define NBLOCKS  512               /* = prefetch stride G */
#define TBYTES   (TILE_M * 256)    /* one bf16 tile: 64 rows x 256 B */

typedef __attribute__((ext_vector_type(8))) short    bf16x8;
typedef __attribute__((ext_vector_type(4))) float    f32x4;
typedef __attribute__((ext_vector_type(4))) unsigned u32x4;
typedef __attribute__((ext_vector_type(2))) unsigned u32x2;

// f32 pair -> packed bf16x2 (RNE) via v_cvt_pk_bf16_f32
static __device__ __forceinline__ unsigned pk2(float a, float b) {
    union { __hip_bfloat162 h; unsigned u; } v;
    v.h = __float22bfloat162_rn(float2{a, b});
    return v.u;
}

union FragU { bf16x8 v; u32x4 u; };

static __device__ __forceinline__ bf16x8 cvt8(const f32x4 a, const f32x4 b) {
    FragU r;
    r.u.x = pk2(a.x, a.y);
    r.u.y = pk2(a.z, a.w);
    r.u.z = pk2(b.x, b.y);
    r.u.w = pk2(b.z, b.w);
    return r.v;
}

static __device__ __forceinline__ float bf2f(unsigned short b) {
    union { unsigned u; float f; } v;
    v.u = ((unsigned)b) << 16;
    return v.f;
}

// Writer-side LDS flush + RAW barrier. Deliberately NOT __syncthreads():
// __syncthreads drains vmcnt(0), which would kill the distance-2 in-flight
// global loads (m97 barrier-drain finding; m201 verified raw s_barrier keeps
// loads in flight). "memory" clobbers pin ds ops on both sides.
static __device__ __forceinline__ void tile_barrier() {
    asm volatile("s_waitcnt lgkmcnt(0)" ::: "memory");
    __builtin_amdgcn_s_barrier();
    asm volatile("" ::: "memory");
}

// out = sigmoid(s@Vs.T + o@Vo.T) * relu(s@Ws.T + o@Wo.T + s*(o.w))
//
// Distance-2 register prefetch (R5) + NONTEMPORAL streaming hints (R6):
// S/O are read exactly once and out written once — zero reuse, so L2
// allocation is pure overhead; nt load/store lets L2 pass them through.
// Weights / w keep default policy (L2/L3 reuse wanted).
__global__ __launch_bounds__(NTHREADS, 2)
void relup_kernel(const float* __restrict__ S, const float* __restrict__ O,
                  const float* __restrict__ Vs, const float* __restrict__ Vo,
                  const float* __restrict__ Ws, const float* __restrict__ Wo,
                  const float* __restrict__ W1, float* __restrict__ out)
{
    // double-buffered bf16 tiles, row stride 256 B, byte-swizzled:
    // 16B granule g of row r lives at (g ^ (r&7))
    __shared__ __align__(16) unsigned char sT[2][TBYTES];
    __shared__ __align__(16) unsigned char oT[2][TBYTES];
    __shared__ float dotv[2][TILE_M];

    const int tid  = threadIdx.x;
    const int lane = tid & 63;
    const int wv   = tid >> 6;       // wave id 0..7, owns output features [wv*16, wv*16+16)
    const int c0   = wv << 4;

    // ---- preload weight fragments into registers (held for whole kernel) ----
    // lane holds W[c0+(lane&15)][kk*32 + (lane>>4)*8 + j] — used as MFMA A operand
    bf16x8 fVs[4], fVo[4], fWs[4], fWo[4];
    {
        const int wr = c0 + (lane & 15);
        const int wc = (lane >> 4) << 3;
        #pragma unroll
        for (int kk = 0; kk < 4; ++kk) {
            const int off = wr * DIM + kk * 32 + wc;
            fVs[kk] = cvt8(*(const f32x4*)(Vs + off), *(const f32x4*)(Vs + off + 4));
            fVo[kk] = cvt8(*(const f32x4*)(Vo + off), *(const f32x4*)(Vo + off + 4));
            fWs[kk] = cvt8(*(const f32x4*)(Ws + off), *(const f32x4*)(Ws + off + 4));
            fWo[kk] = cvt8(*(const f32x4*)(Wo + off), *(const f32x4*)(Wo + off + 4));
        }
    }

    // staging assignment: thread -> (row 0..63, 16-float segment 0..7)
    const int str = tid >> 3;
    const int seg = tid & 7;
    const int swS = (str & 7) << 4;
    const int sb0 = str * 256 + ((seg * 32) ^ swS);
    const int sb1 = str * 256 + (((seg * 32) + 16) ^ swS);

    // w segment held in registers (keeps the pack phase load-free)
    const float* wp = W1 + seg * 16;
    const f32x4 wq0 = ((const f32x4*)wp)[0], wq1 = ((const f32x4*)wp)[1];
    const f32x4 wq2 = ((const f32x4*)wp)[2], wq3 = ((const f32x4*)wp)[3];

    // two register tile sets
    f32x4 As0, As1, As2, As3, Ao0, Ao1, Ao2, Ao3;
    f32x4 Bs0, Bs1, Bs2, Bs3, Bo0, Bo1, Bo2, Bo3;

#define ISSUE(tIdx, Rs0,Rs1,Rs2,Rs3, Ro0,Ro1,Ro2,Ro3) do {                 \
        const f32x4* sp_ = (const f32x4*)(S + ((tIdx) * TILE_M + str) * DIM + seg * 16); \
        const f32x4* op_ = (const f32x4*)(O + ((tIdx) * TILE_M + str) * DIM + seg * 16); \
        Rs0 = __builtin_nontemporal_load(sp_ + 0);                         \
        Rs1 = __builtin_nontemporal_load(sp_ + 1);                         \
        Rs2 = __builtin_nontemporal_load(sp_ + 2);                         \
        Rs3 = __builtin_nontemporal_load(sp_ + 3);                         \
        Ro0 = __builtin_nontemporal_load(op_ + 0);                         \
        Ro1 = __builtin_nontemporal_load(op_ + 1);                         \
        Ro2 = __builtin_nontemporal_load(op_ + 2);                         \
        Ro3 = __builtin_nontemporal_load(op_ + 3);                         \
    } while (0)

#define PACK(buf, Rs0,Rs1,Rs2,Rs3, Ro0,Ro1,Ro2,Ro3) do {                               \
        float p_ = Ro0.x*wq0.x + Ro0.y*wq0.y + Ro0.z*wq0.z + Ro0.w*wq0.w               \
                 + Ro1.x*wq1.x + Ro1.y*wq1.y + Ro1.z*wq1.z + Ro1.w*wq1.w               \
                 + Ro2.x*wq2.x + Ro2.y*wq2.y + Ro2.z*wq2.z + Ro2.w*wq2.w               \
                 + Ro3.x*wq3.x + Ro3.y*wq3.y + Ro3.z*wq3.z + Ro3.w*wq3.w;              \
        u32x4 pa_ = { pk2(Rs0.x,Rs0.y), pk2(Rs0.z,Rs0.w), pk2(Rs1.x,Rs1.y), pk2(Rs1.z,Rs1.w) }; \
        u32x4 pb_ = { pk2(Rs2.x,Rs2.y), pk2(Rs2.z,Rs2.w), pk2(Rs3.x,Rs3.y), pk2(Rs3.z,Rs3.w) }; \
        u32x4 pc_ = { pk2(Ro0.x,Ro0.y), pk2(Ro0.z,Ro0.w), pk2(Ro1.x,Ro1.y), pk2(Ro1.z,Ro1.w) }; \
        u32x4 pd_ = { pk2(Ro2.x,Ro2.y), pk2(Ro2.z,Ro2.w), pk2(Ro3.x,Ro3.y), pk2(Ro3.z,Ro3.w) }; \
        *(u32x4*)(sT[buf] + sb0) = pa_;                                                \
        *(u32x4*)(sT[buf] + sb1) = pb_;                                                \
        *(u32x4*)(oT[buf] + sb0) = pc_;                                                \
        *(u32x4*)(oT[buf] + sb1) = pd_;                                                \
        p_ += __shfl_xor(p_, 1);                                                       \
        p_ += __shfl_xor(p_, 2);                                                       \
        p_ += __shfl_xor(p_, 4);                                                       \
        if (seg == 0) dotv[buf][str] = p_;                                             \
    } while (0)

#define COMPUTE(tIdx, buf) do {                                                        \
        const int row0_ = (tIdx) * TILE_M;                                             \
        const unsigned char* sTc_ = sT[buf];                                           \
        const unsigned char* oTc_ = oT[buf];                                           \
        const float* dvc_ = dotv[buf];                                                 \
        _Pragma("unroll")                                                              \
        for (int b = 0; b < 4; ++b) {                                                  \
            const int r0_  = b << 4;                                                   \
            const int ar_  = r0_ + (lane & 15);                                        \
            const int swA_ = (ar_ & 7) << 4;                                           \
            const int acb_ = (lane >> 4) << 4;                                         \
            bf16x8 fs_[4], fo_[4];                                                     \
            _Pragma("unroll")                                                          \
            for (int kk = 0; kk < 4; ++kk) {                                           \
                const int cb_ = ((kk << 6) + acb_) ^ swA_;                             \
                fs_[kk] = *(const bf16x8*)(sTc_ + ar_ * 256 + cb_);                    \
                fo_[kk] = *(const bf16x8*)(oTc_ + ar_ * 256 + cb_);                    \
            }                                                                          \
            f32x4 accg_ = {0.f, 0.f, 0.f, 0.f};                                        \
            f32x4 accd_ = {0.f, 0.f, 0.f, 0.f};                                        \
            _Pragma("unroll")                                                          \
            for (int kk = 0; kk < 4; ++kk) {                                           \
                accg_ = __builtin_amdgcn_mfma_f32_16x16x32_bf16(fVs[kk], fs_[kk], accg_, 0, 0, 0); \
                accg_ = __builtin_amdgcn_mfma_f32_16x16x32_bf16(fVo[kk], fo_[kk], accg_, 0, 0, 0); \
                accd_ = __builtin_amdgcn_mfma_f32_16x16x32_bf16(fWs[kk], fs_[kk], accd_, 0, 0, 0); \
                accd_ = __builtin_amdgcn_mfma_f32_16x16x32_bf16(fWo[kk], fo_[kk], accd_, 0, 0, 0); \
            }                                                                          \
            /* swapped C/D: lane -> batch row r0+(lane&15), features f0..f0+3 */       \
            const int row_ = r0_ + (lane & 15);                                        \
            const int f0_  = c0 + ((lane >> 4) << 2);                                  \
            const float dv_ = dvc_[row_];                                              \
            const int sOff_ = row_ * 256 + ((2 * f0_) ^ ((row_ & 7) << 4));            \
            const u32x2 sv_ = *(const u32x2*)(sTc_ + sOff_);                           \
            const float sq0_ = bf2f((unsigned short)(sv_.x & 0xffffu));                \
            const float sq1_ = bf2f((unsigned short)(sv_.x >> 16));                    \
            const float sq2_ = bf2f((unsigned short)(sv_.y & 0xffffu));                \
            const float sq3_ = bf2f((unsigned short)(sv_.y >> 16));                    \
            f32x4 res_;                                                                \
            {                                                                          \
                const float g0_ = 1.0f / (1.0f + __expf(-accg_[0]));                   \
                const float g1_ = 1.0f / (1.0f + __expf(-accg_[1]));                   \
                const float g2_ = 1.0f / (1.0f + __expf(-accg_[2]));                   \
                const float g3_ = 1.0f / (1.0f + __expf(-accg_[3]));                   \
                float d0_ = accd_[0] + sq0_ * dv_; d0_ = d0_ > 0.f ? d0_ : 0.f;        \
                float d1_ = accd_[1] + sq1_ * dv_; d1_ = d1_ > 0.f ? d1_ : 0.f;        \
                float d2_ = accd_[2] + sq2_ * dv_; d2_ = d2_ > 0.f ? d2_ : 0.f;        \
                float d3_ = accd_[3] + sq3_ * dv_; d3_ = d3_ > 0.f ? d3_ : 0.f;        \
                res_.x = g0_ * d0_; res_.y = g1_ * d1_;                                \
                res_.z = g2_ * d2_; res_.w = g3_ * d3_;                                \
            }                                                                          \
            __builtin_nontemporal_store(res_, (f32x4*)(out + (row0_ + row_) * DIM + f0_)); \
        }                                                                              \
    } while (0)

    int t = blockIdx.x;

    // ---- prologue: A <- tile t, B <- tile t+G (clamped); pack A -> buf0 ----
    ISSUE(t, As0,As1,As2,As3, Ao0,Ao1,Ao2,Ao3);
    {
        int tB = t + NBLOCKS; if (tB >= NTILES) tB = t;   // clamp: never packed if OOB
        ISSUE(tB, Bs0,Bs1,Bs2,Bs3, Bo0,Bo1,Bo2,Bo3);
    }
    PACK(0, As0,As1,As2,As3, Ao0,Ao1,Ao2,Ao3);
    tile_barrier();

    int cur = 0;
    for (;;) {
        // ---- even body: compute t from buf[cur]; pack B; refill A with t+2G ----
        {
            const bool more1 = (t + NBLOCKS)     < NTILES;
            const bool more2 = (t + 2 * NBLOCKS) < NTILES;
            if (more2) ISSUE(t + 2 * NBLOCKS, As0,As1,As2,As3, Ao0,Ao1,Ao2,Ao3);
            COMPUTE(t, cur);
            if (!more1) break;
            PACK(cur ^ 1, Bs0,Bs1,Bs2,Bs3, Bo0,Bo1,Bo2,Bo3);
            tile_barrier();
            cur ^= 1; t += NBLOCKS;
        }
        // ---- odd body: compute t from buf[cur]; pack A; refill B with t+2G ----
        {
            const bool more1 = (t + NBLOCKS)     < NTILES;
            const bool more2 = (t + 2 * NBLOCKS) < NTILES;
            if (more2) ISSUE(t + 2 * NBLOCKS, Bs0,Bs1,Bs2,Bs3, Bo0,Bo1,Bo2,Bo3);
            COMPUTE(t, cur);
            if (!more1) break;
            PACK(cur ^ 1, As0,As1,As2,As3, Ao0,Ao1,Ao2,Ao3);
            tile_barrier();
            cur ^= 1; t += NBLOCKS;
        }
    }
#undef ISSUE
#undef PACK
#undef COMPUTE
}

extern "C" void kernel_launch(void* const* d_in, const int* in_sizes, int n_in,
                              void* d_out, int out_size, void* d_ws, size_t ws_size,
                              hipStream_t stream) {
    const float* S  = (const float*)d_in[0];
    const float* O  = (const float*)d_in[1];
    const float* Vs = (const float*)d_in[2];
    const float* Vo = (const float*)d_in[3];
    const float* Ws = (const float*)d_in[4];
    const float* Wo = (const float*)d_in[5];
    const float* w  = (const float*)d_in[6];
    float* out = (float*)d_out;
    relup_kernel<<<NBLOCKS, NTHREADS, 0, stream>>>(S, O, Vs, Vo, Ws, Wo, w, out);
}

// Round 7
// 305.499 us; speedup vs baseline: 1.4342x; 1.4342x over previous
//
#include <hip/hip_runtime.h>
#include <hip/hip_bf16.h>

#define BR_N     1000000
#define DIM      128
#define TILE_M   64
#define NTILES   (BR_N / TILE_M)   /* 15625, exact */
#define NTHREADS 512
#define NBLOCKS  512               /* = prefetch stride G */
#define TBYTES   (TILE_M * 256)    /* one bf16 tile: 64 rows x 256 B */

typedef __attribute__((ext_vector_type(8))) short    bf16x8;
typedef __attribute__((ext_vector_type(4))) float    f32x4;
typedef __attribute__((ext_vector_type(4))) unsigned u32x4;
typedef __attribute__((ext_vector_type(2))) unsigned u32x2;

// f32 pair -> packed bf16x2 (RNE) via v_cvt_pk_bf16_f32
static __device__ __forceinline__ unsigned pk2(float a, float b) {
    union { __hip_bfloat162 h; unsigned u; } v;
    v.h = __float22bfloat162_rn(float2{a, b});
    return v.u;
}

union FragU { bf16x8 v; u32x4 u; };

static __device__ __forceinline__ bf16x8 cvt8(const f32x4 a, const f32x4 b) {
    FragU r;
    r.u.x = pk2(a.x, a.y);
    r.u.y = pk2(a.z, a.w);
    r.u.z = pk2(b.x, b.y);
    r.u.w = pk2(b.z, b.w);
    return r.v;
}

static __device__ __forceinline__ float bf2f(unsigned short b) {
    union { unsigned u; float f; } v;
    v.u = ((unsigned)b) << 16;
    return v.f;
}

// Writer-side LDS flush + RAW barrier. Deliberately NOT __syncthreads():
// __syncthreads drains vmcnt(0), which would kill the distance-2 in-flight
// global loads (m97 barrier-drain finding; m201 verified raw s_barrier keeps
// loads in flight). "memory" clobbers pin ds ops on both sides.
static __device__ __forceinline__ void tile_barrier() {
    asm volatile("s_waitcnt lgkmcnt(0)" ::: "memory");
    __builtin_amdgcn_s_barrier();
    asm volatile("" ::: "memory");
}

// out = sigmoid(s@Vs.T + o@Vo.T) * relu(s@Ws.T + o@Wo.T + s*(o.w))
//
// Distance-2 register prefetch: two tile register sets (A/B). Iteration m:
// issue loads for tile t+2G into the set freed last iteration, MFMA tile t
// from LDS[cur], pack tile t+G (loaded one FULL iteration ago -> HBM latency
// + queue time covered), raw-barrier.
//
// NOTE (R6 post-mortem): do NOT use __builtin_nontemporal_load/store here.
// NT stores bypass L2 write-combining -> partial-line RMW at HBM:
// WRITE_SIZE 500->650 MB, FETCH 502->635 MB, dur 303->438 us. Default
// policy merges the 8 waves' 64B row-chunks perfectly (WRITE == output size).
__global__ __launch_bounds__(NTHREADS, 2)
void relup_kernel(const float* __restrict__ S, const float* __restrict__ O,
                  const float* __restrict__ Vs, const float* __restrict__ Vo,
                  const float* __restrict__ Ws, const float* __restrict__ Wo,
                  const float* __restrict__ W1, float* __restrict__ out)
{
    // double-buffered bf16 tiles, row stride 256 B, byte-swizzled:
    // 16B granule g of row r lives at (g ^ (r&7))
    __shared__ __align__(16) unsigned char sT[2][TBYTES];
    __shared__ __align__(16) unsigned char oT[2][TBYTES];
    __shared__ float dotv[2][TILE_M];

    const int tid  = threadIdx.x;
    const int lane = tid & 63;
    const int wv   = tid >> 6;       // wave id 0..7, owns output features [wv*16, wv*16+16)
    const int c0   = wv << 4;

    // ---- preload weight fragments into registers (held for whole kernel) ----
    // lane holds W[c0+(lane&15)][kk*32 + (lane>>4)*8 + j] — used as MFMA A operand
    bf16x8 fVs[4], fVo[4], fWs[4], fWo[4];
    {
        const int wr = c0 + (lane & 15);
        const int wc = (lane >> 4) << 3;
        #pragma unroll
        for (int kk = 0; kk < 4; ++kk) {
            const int off = wr * DIM + kk * 32 + wc;
            fVs[kk] = cvt8(*(const f32x4*)(Vs + off), *(const f32x4*)(Vs + off + 4));
            fVo[kk] = cvt8(*(const f32x4*)(Vo + off), *(const f32x4*)(Vo + off + 4));
            fWs[kk] = cvt8(*(const f32x4*)(Ws + off), *(const f32x4*)(Ws + off + 4));
            fWo[kk] = cvt8(*(const f32x4*)(Wo + off), *(const f32x4*)(Wo + off + 4));
        }
    }

    // staging assignment: thread -> (row 0..63, 16-float segment 0..7)
    const int str = tid >> 3;
    const int seg = tid & 7;
    const int swS = (str & 7) << 4;
    const int sb0 = str * 256 + ((seg * 32) ^ swS);
    const int sb1 = str * 256 + (((seg * 32) + 16) ^ swS);

    // w segment held in registers (keeps the pack phase load-free)
    const float* wp = W1 + seg * 16;
    const f32x4 wq0 = ((const f32x4*)wp)[0], wq1 = ((const f32x4*)wp)[1];
    const f32x4 wq2 = ((const f32x4*)wp)[2], wq3 = ((const f32x4*)wp)[3];

    // two register tile sets
    f32x4 As0, As1, As2, As3, Ao0, Ao1, Ao2, Ao3;
    f32x4 Bs0, Bs1, Bs2, Bs3, Bo0, Bo1, Bo2, Bo3;

#define ISSUE(tIdx, Rs0,Rs1,Rs2,Rs3, Ro0,Ro1,Ro2,Ro3) do {                 \
        const float* sp_ = S + ((tIdx) * TILE_M + str) * DIM + seg * 16;   \
        const float* op_ = O + ((tIdx) * TILE_M + str) * DIM + seg * 16;   \
        Rs0 = ((const f32x4*)sp_)[0]; Rs1 = ((const f32x4*)sp_)[1];        \
        Rs2 = ((const f32x4*)sp_)[2]; Rs3 = ((const f32x4*)sp_)[3];        \
        Ro0 = ((const f32x4*)op_)[0]; Ro1 = ((const f32x4*)op_)[1];        \
        Ro2 = ((const f32x4*)op_)[2]; Ro3 = ((const f32x4*)op_)[3];        \
    } while (0)

#define PACK(buf, Rs0,Rs1,Rs2,Rs3, Ro0,Ro1,Ro2,Ro3) do {                               \
        float p_ = Ro0.x*wq0.x + Ro0.y*wq0.y + Ro0.z*wq0.z + Ro0.w*wq0.w               \
                 + Ro1.x*wq1.x + Ro1.y*wq1.y + Ro1.z*wq1.z + Ro1.w*wq1.w               \
                 + Ro2.x*wq2.x + Ro2.y*wq2.y + Ro2.z*wq2.z + Ro2.w*wq2.w               \
                 + Ro3.x*wq3.x + Ro3.y*wq3.y + Ro3.z*wq3.z + Ro3.w*wq3.w;              \
        u32x4 pa_ = { pk2(Rs0.x,Rs0.y), pk2(Rs0.z,Rs0.w), pk2(Rs1.x,Rs1.y), pk2(Rs1.z,Rs1.w) }; \
        u32x4 pb_ = { pk2(Rs2.x,Rs2.y), pk2(Rs2.z,Rs2.w), pk2(Rs3.x,Rs3.y), pk2(Rs3.z,Rs3.w) }; \
        u32x4 pc_ = { pk2(Ro0.x,Ro0.y), pk2(Ro0.z,Ro0.w), pk2(Ro1.x,Ro1.y), pk2(Ro1.z,Ro1.w) }; \
        u32x4 pd_ = { pk2(Ro2.x,Ro2.y), pk2(Ro2.z,Ro2.w), pk2(Ro3.x,Ro3.y), pk2(Ro3.z,Ro3.w) }; \
        *(u32x4*)(sT[buf] + sb0) = pa_;                                                \
        *(u32x4*)(sT[buf] + sb1) = pb_;                                                \
        *(u32x4*)(oT[buf] + sb0) = pc_;                                                \
        *(u32x4*)(oT[buf] + sb1) = pd_;                                                \
        p_ += __shfl_xor(p_, 1);                                                       \
        p_ += __shfl_xor(p_, 2);                                                       \
        p_ += __shfl_xor(p_, 4);                                                       \
        if (seg == 0) dotv[buf][str] = p_;                                             \
    } while (0)

#define COMPUTE(tIdx, buf) do {                                                        \
        const int row0_ = (tIdx) * TILE_M;                                             \
        const unsigned char* sTc_ = sT[buf];                                           \
        const unsigned char* oTc_ = oT[buf];                                           \
        const float* dvc_ = dotv[buf];                                                 \
        _Pragma("unroll")                                                              \
        for (int b = 0; b < 4; ++b) {                                                  \
            const int r0_  = b << 4;                                                   \
            const int ar_  = r0_ + (lane & 15);                                        \
            const int swA_ = (ar_ & 7) << 4;                                           \
            const int acb_ = (lane >> 4) << 4;                                         \
            bf16x8 fs_[4], fo_[4];                                                     \
            _Pragma("unroll")                                                          \
            for (int kk = 0; kk < 4; ++kk) {                                           \
                const int cb_ = ((kk << 6) + acb_) ^ swA_;                             \
                fs_[kk] = *(const bf16x8*)(sTc_ + ar_ * 256 + cb_);                    \
                fo_[kk] = *(const bf16x8*)(oTc_ + ar_ * 256 + cb_);                    \
            }                                                                          \
            f32x4 accg_ = {0.f, 0.f, 0.f, 0.f};                                        \
            f32x4 accd_ = {0.f, 0.f, 0.f, 0.f};                                        \
            _Pragma("unroll")                                                          \
            for (int kk = 0; kk < 4; ++kk) {                                           \
                accg_ = __builtin_amdgcn_mfma_f32_16x16x32_bf16(fVs[kk], fs_[kk], accg_, 0, 0, 0); \
                accg_ = __builtin_amdgcn_mfma_f32_16x16x32_bf16(fVo[kk], fo_[kk], accg_, 0, 0, 0); \
                accd_ = __builtin_amdgcn_mfma_f32_16x16x32_bf16(fWs[kk], fs_[kk], accd_, 0, 0, 0); \
                accd_ = __builtin_amdgcn_mfma_f32_16x16x32_bf16(fWo[kk], fo_[kk], accd_, 0, 0, 0); \
            }                                                                          \
            /* swapped C/D: lane -> batch row r0+(lane&15), features f0..f0+3 */       \
            const int row_ = r0_ + (lane & 15);                                        \
            const int f0_  = c0 + ((lane >> 4) << 2);                                  \
            const float dv_ = dvc_[row_];                                              \
            const int sOff_ = row_ * 256 + ((2 * f0_) ^ ((row_ & 7) << 4));            \
            const u32x2 sv_ = *(const u32x2*)(sTc_ + sOff_);                           \
            const float sq0_ = bf2f((unsigned short)(sv_.x & 0xffffu));                \
            const float sq1_ = bf2f((unsigned short)(sv_.x >> 16));                    \
            const float sq2_ = bf2f((unsigned short)(sv_.y & 0xffffu));                \
            const float sq3_ = bf2f((unsigned short)(sv_.y >> 16));                    \
            f32x4 res_;                                                                \
            {                                                                          \
                const float g0_ = 1.0f / (1.0f + __expf(-accg_[0]));                   \
                const float g1_ = 1.0f / (1.0f + __expf(-accg_[1]));                   \
                const float g2_ = 1.0f / (1.0f + __expf(-accg_[2]));                   \
                const float g3_ = 1.0f / (1.0f + __expf(-accg_[3]));                   \
                float d0_ = accd_[0] + sq0_ * dv_; d0_ = d0_ > 0.f ? d0_ : 0.f;        \
                float d1_ = accd_[1] + sq1_ * dv_; d1_ = d1_ > 0.f ? d1_ : 0.f;        \
                float d2_ = accd_[2] + sq2_ * dv_; d2_ = d2_ > 0.f ? d2_ : 0.f;        \
                float d3_ = accd_[3] + sq3_ * dv_; d3_ = d3_ > 0.f ? d3_ : 0.f;        \
                res_.x = g0_ * d0_; res_.y = g1_ * d1_;                                \
                res_.z = g2_ * d2_; res_.w = g3_ * d3_;                                \
            }                                                                          \
            *(f32x4*)(out + (row0_ + row_) * DIM + f0_) = res_;                        \
        }                                                                              \
    } while (0)

    int t = blockIdx.x;

    // ---- prologue: A <- tile t, B <- tile t+G (clamped); pack A -> buf0 ----
    ISSUE(t, As0,As1,As2,As3, Ao0,Ao1,Ao2,Ao3);
    {
        int tB = t + NBLOCKS; if (tB >= NTILES) tB = t;   // clamp: never packed if OOB
        ISSUE(tB, Bs0,Bs1,Bs2,Bs3, Bo0,Bo1,Bo2,Bo3);
    }
    PACK(0, As0,As1,As2,As3, Ao0,Ao1,Ao2,Ao3);
    tile_barrier();

    int cur = 0;
    for (;;) {
        // ---- even body: compute t from buf[cur]; pack B; refill A with t+2G ----
        {
            const bool more1 = (t + NBLOCKS)     < NTILES;
            const bool more2 = (t + 2 * NBLOCKS) < NTILES;
            if (more2) ISSUE(t + 2 * NBLOCKS, As0,As1,As2,As3, Ao0,Ao1,Ao2,Ao3);
            COMPUTE(t, cur);
            if (!more1) break;
            PACK(cur ^ 1, Bs0,Bs1,Bs2,Bs3, Bo0,Bo1,Bo2,Bo3);
            tile_barrier();
            cur ^= 1; t += NBLOCKS;
        }
        // ---- odd body: compute t from buf[cur]; pack A; refill B with t+2G ----
        {
            const bool more1 = (t + NBLOCKS)     < NTILES;
            const bool more2 = (t + 2 * NBLOCKS) < NTILES;
            if (more2) ISSUE(t + 2 * NBLOCKS, Bs0,Bs1,Bs2,Bs3, Bo0,Bo1,Bo2,Bo3);
            COMPUTE(t, cur);
            if (!more1) break;
            PACK(cur ^ 1, As0,As1,As2,As3, Ao0,Ao1,Ao2,Ao3);
            tile_barrier();
            cur ^= 1; t += NBLOCKS;
        }
    }
#undef ISSUE
#undef PACK
#undef COMPUTE
}

extern "C" void kernel_launch(void* const* d_in, const int* in_sizes, int n_in,
                              void* d_out, int out_size, void* d_ws, size_t ws_size,
                              hipStream_t stream) {
    const float* S  = (const float*)d_in[0];
    const float* O  = (const float*)d_in[1];
    const float* Vs = (const float*)d_in[2];
    const float* Vo = (const float*)d_in[3];
    const float* Ws = (const float*)d_in[4];
    const float* Wo = (const float*)d_in[5];
    const float* w  = (const float*)d_in[6];
    float* out = (float*)d_out;
    relup_kernel<<<NBLOCKS, NTHREADS, 0, stream>>>(S, O, Vs, Vo, Ws, Wo, w, out);
}